// Round 10
// baseline (51.342 us; speedup 1.0000x reference)
//
#include <hip/hip_runtime.h>

#define Cc 8
#define Hh 128
#define Ww 128
#define Nn 64
#define Bb 8
#define Dd 169            // (C+2)*C + C + C*C + C + C + 1
#define HW (Hh * Ww)
#define CHUNKS 4          // blocks per (b,n)
#define NBLK (Bb * Nn * CHUNKS)   // 2048
#define PXB (HW / CHUNKS)         // 4096 px per block
#define GROUPS 4                  // 4 float4-groups -> 16 px per thread
#define WSTRIDE 88                // u32 per bn in packed table (85 used)
#define RED_OFF (Bb * Nn * WSTRIDE)  // float offset of reduction slots in ws

#define INV128 (1.0f / 128.0f)

typedef __fp16 f16x2 __attribute__((ext_vector_type(2)));

static __device__ __forceinline__ f16x2 pk(float a, float b) {
    return __builtin_amdgcn_cvt_pkrtz(a, b);   // v_cvt_pkrtz_f16_f32
}
static __device__ __forceinline__ uint32_t pku(float a, float b) {
    f16x2 t = pk(a, b); uint32_t u; __builtin_memcpy(&u, &t, 4); return u;
}
static __device__ __forceinline__ f16x2 u2h(uint32_t u) {
    f16x2 r; __builtin_memcpy(&r, &u, 4); return r;
}

#if __has_builtin(__builtin_amdgcn_fdot2)
static __device__ __forceinline__ float dot2(uint32_t w, f16x2 f, float acc) {
    return __builtin_amdgcn_fdot2(u2h(w), f, acc, false);   // v_dot2_f32_f16
}
#else
static __device__ __forceinline__ float dot2(uint32_t w, f16x2 f, float acc) {
    f16x2 wv = u2h(w);
    return acc + (float)wv.x * (float)f.x + (float)wv.y * (float)f.y;
}
#endif

static __device__ __forceinline__ float pick(float4 v, int j) {
    return j == 0 ? v.x : j == 1 ? v.y : j == 2 ? v.z : v.w;
}

// ---- kernel A: gather + f16-pack the per-bn weight vectors (once) ----
// pair layout (u32 idx): [0..39]=w1 rows (5 pairs/row: (c0,c1)(c2,c3)(c4,c5)(c6,c7)(w8,w9)),
// [40..71]=w2 rows (4/row), [72..75]=w3, [76..79]=b1, [80..83]=b2, [84]=(b3,0)
__global__ void pack_weights(const float* __restrict__ conv_weight,
                             const int*   __restrict__ ind,
                             uint32_t*    __restrict__ wt) {
    const int bn = blockIdx.x;       // 512
    const int j  = threadIdx.x;      // 96 threads
    const int b  = bn >> 6;
    const int ind_bn = ind[bn];
    const float* src = conv_weight + (size_t)b * Dd * HW + ind_bn;
    if (j < 85) {
        int d0, d1;
        if (j < 40)      { d0 = (j / 5) * 10 + (j % 5) * 2; d1 = d0 + 1; }
        else if (j < 72) { d0 = 88  + 2 * (j - 40); d1 = d0 + 1; }
        else if (j < 76) { d0 = 160 + 2 * (j - 72); d1 = d0 + 1; }
        else if (j < 80) { d0 = 80  + 2 * (j - 76); d1 = d0 + 1; }
        else if (j < 84) { d0 = 152 + 2 * (j - 80); d1 = d0 + 1; }
        else             { d0 = 168; d1 = -1; }
        const float a = src[(size_t)d0 * HW];
        const float c = (d1 >= 0) ? src[(size_t)d1 * HW] : 0.f;
        wt[bn * WSTRIDE + j] = pku(a, c);
    }
}

// ---- kernel B: MLP + dice; weights PINNED in VGPRs via opaque asm ----
__global__ __launch_bounds__(256)
__attribute__((amdgpu_waves_per_eu(2, 4)))
void seg_dice_main(const float* __restrict__ seg_feat,
                   const float* __restrict__ mask,
                   const int*   __restrict__ ind,
                   const float* __restrict__ target,
                   const uint32_t* __restrict__ wtab,
                   float* __restrict__ red_base) {
    const int g     = (blockIdx.x & 7) * (NBLK / 8) + (blockIdx.x >> 3);
    const int bn    = g >> 2;
    const int chunk = g & (CHUNKS - 1);
    const int b     = bn >> 6;
    const int tid   = threadIdx.x;

    // vector-load the packed table (opaque address defeats scalarization),
    // then PIN weights in VGPRs so the compiler cannot reload/rematerialize.
    uint32_t wq[88];
    {
        uint64_t addr = (uint64_t)(wtab + bn * WSTRIDE);
        asm volatile("" : "+v"(addr));
        const uint4* wt4 = (const uint4*)addr;
        #pragma unroll
        for (int k = 0; k < 22; ++k) {
            const uint4 q = wt4[k];
            wq[4 * k + 0] = q.x; wq[4 * k + 1] = q.y;
            wq[4 * k + 2] = q.z; wq[4 * k + 3] = q.w;
        }
    }
    // biases -> f32 registers
    float b1f[8], b2f[8];
    #pragma unroll
    for (int k = 0; k < 4; ++k) {
        const f16x2 v1 = u2h(wq[76 + k]); b1f[2 * k] = (float)v1.x; b1f[2 * k + 1] = (float)v1.y;
        const f16x2 v2 = u2h(wq[80 + k]); b2f[2 * k] = (float)v2.x; b2f[2 * k + 1] = (float)v2.y;
    }
    float b3f = (float)u2h(wq[84]).x;

    #pragma unroll
    for (int j = 0; j < 76; ++j) asm volatile("" : "+v"(wq[j]));
    #pragma unroll
    for (int o = 0; o < 8; ++o) {
        asm volatile("" : "+v"(b1f[o]));
        asm volatile("" : "+v"(b2f[o]));
    }
    asm volatile("" : "+v"(b3f));

    const int   ind_bn = ind[bn];
    const float m  = mask[bn];
    const float x0 = (float)(ind_bn & (Ww - 1));
    const float y0 = (float)(ind_bn >> 7);

    const float* seg_b  = seg_feat + (size_t)b * Cc * HW;
    const float* tgt_bn = target   + (size_t)bn * HW;

    float inter = 0.f, ps = 0.f, ts = 0.f;
    const int pbase = chunk * PXB + (tid << 2);

    #pragma unroll 1
    for (int it = 0; it < GROUPS; ++it) {
        const int p = pbase + (it << 10);

        const float4 t4 = *(const float4*)(tgt_bn + p);
        float4 f4[8];
        #pragma unroll
        for (int c = 0; c < 8; ++c) f4[c] = *(const float4*)(seg_b + c * HW + p);

        const float yrf = ((float)(p >> 7)        - y0) * INV128;
        const float xbf = ((float)(p & (Ww - 1)) - x0) * INV128;

        #pragma unroll
        for (int j = 0; j < 4; ++j) {
            const f16x2 fp0 = pk(pick(f4[0], j), pick(f4[1], j));
            const f16x2 fp1 = pk(pick(f4[2], j), pick(f4[3], j));
            const f16x2 fp2 = pk(pick(f4[4], j), pick(f4[5], j));
            const f16x2 fp3 = pk(pick(f4[6], j), pick(f4[7], j));
            const f16x2 fpx = pk(xbf + (float)j * INV128, yrf);

            // layer 1: acc starts at bias (dot2 src2) -- no movs
            float h1[8];
            #pragma unroll
            for (int o = 0; o < 8; ++o) {
                float a = dot2(wq[5 * o + 4], fpx, b1f[o]);
                a = dot2(wq[5 * o + 0], fp0, a);
                a = dot2(wq[5 * o + 1], fp1, a);
                a = dot2(wq[5 * o + 2], fp2, a);
                a = dot2(wq[5 * o + 3], fp3, a);
                h1[o] = fmaxf(a, 0.f);
            }
            const f16x2 hp0 = pk(h1[0], h1[1]);
            const f16x2 hp1 = pk(h1[2], h1[3]);
            const f16x2 hp2 = pk(h1[4], h1[5]);
            const f16x2 hp3 = pk(h1[6], h1[7]);

            float h2[8];
            #pragma unroll
            for (int o = 0; o < 8; ++o) {
                float a = dot2(wq[40 + 4 * o + 0], hp0, b2f[o]);
                a = dot2(wq[40 + 4 * o + 1], hp1, a);
                a = dot2(wq[40 + 4 * o + 2], hp2, a);
                a = dot2(wq[40 + 4 * o + 3], hp3, a);
                h2[o] = fmaxf(a, 0.f);
            }
            const f16x2 gp0 = pk(h2[0], h2[1]);
            const f16x2 gp1 = pk(h2[2], h2[3]);
            const f16x2 gp2 = pk(h2[4], h2[5]);
            const f16x2 gp3 = pk(h2[6], h2[7]);

            float z = dot2(wq[72], gp0, b3f);
            z = dot2(wq[73], gp1, z);
            z = dot2(wq[74], gp2, z);
            z = dot2(wq[75], gp3, z);

            const float o_ = __builtin_amdgcn_rcpf(1.f + __expf(-z));
            const float tv = pick(t4, j);
            inter = fmaf(o_, tv, inter);
            ps    = fmaf(o_, o_, ps);
            ts    = fmaf(tv, tv, ts);
        }
    }

    const float m2 = m * m;
    inter *= m2; ps *= m2; ts *= m2;

    #pragma unroll
    for (int off = 32; off > 0; off >>= 1) {
        inter += __shfl_down(inter, off);
        ps    += __shfl_down(ps,    off);
        ts    += __shfl_down(ts,    off);
    }
    __shared__ float red[3][4];
    const int wave = tid >> 6;
    if ((tid & 63) == 0) { red[0][wave] = inter; red[1][wave] = ps; red[2][wave] = ts; }
    __syncthreads();
    if (tid == 0) {
        const int local = (bn & 63) * CHUNKS + chunk;   // 0..255 within batch b
        red_base[(b * 3 + 0) * 256 + local] = red[0][0] + red[0][1] + red[0][2] + red[0][3];
        red_base[(b * 3 + 1) * 256 + local] = red[1][0] + red[1][1] + red[1][2] + red[1][3];
        red_base[(b * 3 + 2) * 256 + local] = red[2][0] + red[2][1] + red[2][2] + red[2][3];
    }
}

// deterministic epilogue: 24 series (8 b x 3 comps) x 256 partials
__global__ void seg_dice_final(const float* __restrict__ red_base, float* __restrict__ out) {
    __shared__ float red[24][4];
    const int tid = threadIdx.x;  // 128 threads
    if (tid < 96) {
        const int series = tid >> 2;   // 0..23
        const int part   = tid & 3;    // 0..3
        const float4* p = (const float4*)(red_base + series * 256 + part * 64);
        float s = 0.f;
        #pragma unroll
        for (int i = 0; i < 16; ++i) { const float4 v = p[i]; s += (v.x + v.y) + (v.z + v.w); }
        red[series][part] = s;
    }
    __syncthreads();
    if (tid == 0) {
        float acc = 0.f;
        #pragma unroll
        for (int b = 0; b < Bb; ++b) {
            const float inter = red[b*3+0][0] + red[b*3+0][1] + red[b*3+0][2] + red[b*3+0][3];
            const float p2    = red[b*3+1][0] + red[b*3+1][1] + red[b*3+1][2] + red[b*3+1][3];
            const float t2    = red[b*3+2][0] + red[b*3+2][1] + red[b*3+2][2] + red[b*3+2][3];
            acc += 1.0f - (2.0f * inter + 1.0f) / (p2 + t2 + 1.0f);
        }
        out[0] = acc * (1.0f / (float)Bb);
    }
}

extern "C" void kernel_launch(void* const* d_in, const int* in_sizes, int n_in,
                              void* d_out, int out_size, void* d_ws, size_t ws_size,
                              hipStream_t stream) {
    const float* seg_feat    = (const float*)d_in[0];
    const float* conv_weight = (const float*)d_in[1];
    const float* mask        = (const float*)d_in[2];
    const int*   ind         = (const int*)d_in[3];
    const float* target      = (const float*)d_in[4];
    float* out = (float*)d_out;
    float* ws  = (float*)d_ws;

    uint32_t* wtab     = (uint32_t*)ws;
    float*    red_base = ws + RED_OFF;

    pack_weights<<<Bb * Nn, 96, 0, stream>>>(conv_weight, ind, wtab);
    seg_dice_main<<<NBLK, 256, 0, stream>>>(seg_feat, mask, ind, target, wtab, red_base);
    seg_dice_final<<<1, 128, 0, stream>>>(red_base, out);
}

// Round 11
// 41.549 us; speedup vs baseline: 1.2357x; 1.2357x over previous
//
#include <hip/hip_runtime.h>

#define Cc 8
#define Hh 128
#define Ww 128
#define Nn 64
#define Bb 8
#define Dd 169            // (C+2)*C + C + C*C + C + C + 1
#define HW (Hh * Ww)
#define CHUNKS 4          // blocks per (b,n)
#define NBLK (Bb * Nn * CHUNKS)   // 2048
#define PXB (HW / CHUNKS)         // 4096 px per block
#define GROUPS 4                  // 4 float4-groups -> 16 px per thread
#define WSTRIDE 88                // u32 per bn in packed table (85 used)
#define RED_OFF (Bb * Nn * WSTRIDE)  // float offset of reduction slots in ws

#define INV128 (1.0f / 128.0f)

typedef __fp16 f16x2 __attribute__((ext_vector_type(2)));

static __device__ __forceinline__ f16x2 pk(float a, float b) {
    return __builtin_amdgcn_cvt_pkrtz(a, b);   // v_cvt_pkrtz_f16_f32
}
static __device__ __forceinline__ uint32_t pku(float a, float b) {
    f16x2 t = pk(a, b); uint32_t u; __builtin_memcpy(&u, &t, 4); return u;
}
static __device__ __forceinline__ f16x2 u2h(uint32_t u) {
    f16x2 r; __builtin_memcpy(&r, &u, 4); return r;
}
static __device__ __forceinline__ f16x2 max2(f16x2 a, f16x2 b) {
    return __builtin_elementwise_max(a, b);    // v_pk_max_f16
}

// ---- full-rate pk_fma with SGPR weight-pair broadcast via op_sel ----
// acc += w.lo * f   (w pair in SGPR; lo half broadcast to both lanes)
static __device__ __forceinline__ void fma_lo(f16x2& acc, uint32_t w, f16x2 f) {
    asm("v_pk_fma_f16 %0, %1, %2, %0 op_sel:[0,0,0] op_sel_hi:[0,1,1]"
        : "+v"(acc) : "s"(w), "v"(f));
}
// acc += w.hi * f
static __device__ __forceinline__ void fma_hi(f16x2& acc, uint32_t w, f16x2 f) {
    asm("v_pk_fma_f16 %0, %1, %2, %0 op_sel:[1,0,0] op_sel_hi:[1,1,1]"
        : "+v"(acc) : "s"(w), "v"(f));
}
// out = w.lo * f + c   (4-operand form: no acc-init mov)
static __device__ __forceinline__ f16x2 fma_lo4(uint32_t w, f16x2 f, f16x2 c) {
    f16x2 o;
    asm("v_pk_fma_f16 %0, %1, %2, %3 op_sel:[0,0,0] op_sel_hi:[0,1,1]"
        : "=v"(o) : "s"(w), "v"(f), "v"(c));
    return o;
}
// out = w.hi * f + c
static __device__ __forceinline__ f16x2 fma_hi4(uint32_t w, f16x2 f, f16x2 c) {
    f16x2 o;
    asm("v_pk_fma_f16 %0, %1, %2, %3 op_sel:[1,0,0] op_sel_hi:[1,1,1]"
        : "=v"(o) : "s"(w), "v"(f), "v"(c));
    return o;
}

static __device__ __forceinline__ float pick(float4 v, int j) {
    return j == 0 ? v.x : j == 1 ? v.y : j == 2 ? v.z : v.w;
}

// ---- kernel A: gather + f16-pack the per-bn weight vectors (once) ----
// pair layout (u32 idx): [0..39]=w1 rows (5 pairs/row: (c0,c1)(c2,c3)(c4,c5)(c6,c7)(w8,w9)),
// [40..71]=w2 rows (4/row), [72..75]=w3, [76..79]=b1, [80..83]=b2, [84]=(b3,0)
__global__ void pack_weights(const float* __restrict__ conv_weight,
                             const int*   __restrict__ ind,
                             uint32_t*    __restrict__ wt) {
    const int bn = blockIdx.x;       // 512
    const int j  = threadIdx.x;      // 96 threads
    const int b  = bn >> 6;
    const int ind_bn = ind[bn];
    const float* src = conv_weight + (size_t)b * Dd * HW + ind_bn;
    if (j < 85) {
        int d0, d1;
        if (j < 40)      { d0 = (j / 5) * 10 + (j % 5) * 2; d1 = d0 + 1; }
        else if (j < 72) { d0 = 88  + 2 * (j - 40); d1 = d0 + 1; }
        else if (j < 76) { d0 = 160 + 2 * (j - 72); d1 = d0 + 1; }
        else if (j < 80) { d0 = 80  + 2 * (j - 76); d1 = d0 + 1; }
        else if (j < 84) { d0 = 152 + 2 * (j - 80); d1 = d0 + 1; }
        else             { d0 = 168; d1 = -1; }
        const float a = src[(size_t)d0 * HW];
        const float c = (d1 >= 0) ? src[(size_t)d1 * HW] : 0.f;
        wt[bn * WSTRIDE + j] = pku(a, c);
    }
}

// ---- kernel B: MLP + dice; weights SGPR-resident, op_sel splat, pk_fma ----
__global__ __launch_bounds__(256)
void seg_dice_main(const float* __restrict__ seg_feat,
                   const float* __restrict__ mask,
                   const int*   __restrict__ ind,
                   const float* __restrict__ target,
                   const uint32_t* __restrict__ wtab,
                   float* __restrict__ red_base) {
    const int g     = (blockIdx.x & 7) * (NBLK / 8) + (blockIdx.x >> 3);
    const int chunk = g & (CHUNKS - 1);
    // force provable uniformity -> s_load into SGPRs
    const int bnu = __builtin_amdgcn_readfirstlane(g >> 2);
    const int b   = bnu >> 6;
    const int tid = threadIdx.x;

    // block-uniform packed table -> SGPRs (pairs; NO vgpr pins)
    uint32_t wq[88];
    {
        const uint4* wt4 = (const uint4*)(wtab + bnu * WSTRIDE);
        #pragma unroll
        for (int k = 0; k < 22; ++k) {
            const uint4 q = wt4[k];
            wq[4 * k + 0] = q.x; wq[4 * k + 1] = q.y;
            wq[4 * k + 2] = q.z; wq[4 * k + 3] = q.w;
        }
    }
    // biases -> splat f16x2 VGPRs (17 regs, one-time)
    f16x2 b1v[8], b2v[8];
    #pragma unroll
    for (int k = 0; k < 4; ++k) {
        const f16x2 p1 = u2h(wq[76 + k]);
        b1v[2 * k]     = f16x2{p1.x, p1.x};
        b1v[2 * k + 1] = f16x2{p1.y, p1.y};
        const f16x2 p2 = u2h(wq[80 + k]);
        b2v[2 * k]     = f16x2{p2.x, p2.x};
        b2v[2 * k + 1] = f16x2{p2.y, p2.y};
    }
    const f16x2 pb3 = u2h(wq[84]);
    const f16x2 b3v = f16x2{pb3.x, pb3.x};

    const int   ind_bn = ind[bnu];
    const float m  = mask[bnu];
    const float x0 = (float)(ind_bn & (Ww - 1));
    const float y0 = (float)(ind_bn >> 7);

    const float* seg_b  = seg_feat + (size_t)b * Cc * HW;
    const float* tgt_bn = target   + (size_t)bnu * HW;

    float inter = 0.f, ps = 0.f, ts = 0.f;
    const int pbase = chunk * PXB + (tid << 2);

    #pragma unroll 1
    for (int it = 0; it < GROUPS; ++it) {
        const int p = pbase + (it << 10);

        const float4 t4 = *(const float4*)(tgt_bn + p);
        float4 f4[8];
        #pragma unroll
        for (int c = 0; c < 8; ++c) f4[c] = *(const float4*)(seg_b + c * HW + p);

        const float yrf = ((float)(p >> 7)        - y0) * INV128;
        const float xbf = ((float)(p & (Ww - 1)) - x0) * INV128;
        const f16x2 yr2  = pk(yrf, yrf);
        const f16x2 xr01 = pk(xbf, xbf + INV128);
        const f16x2 xr23 = pk(xbf + 2.f * INV128, xbf + 3.f * INV128);

        // feature px-pairs: fA=(px0,px1), fB=(px2,px3) per channel
        f16x2 fA[8], fB[8];
        #pragma unroll
        for (int c = 0; c < 8; ++c) {
            fA[c] = pk(f4[c].x, f4[c].y);
            fB[c] = pk(f4[c].z, f4[c].w);
        }

        // ---- layer 1: 10 -> 8, relu ----
        f16x2 h1A[8], h1B[8];
        #pragma unroll
        for (int o = 0; o < 8; ++o) {
            const uint32_t wxy = wq[5 * o + 4];          // (w8, w9)
            const f16x2 base = fma_hi4(wxy, yr2, b1v[o]); // w9*yr + b1
            f16x2 a01 = fma_lo4(wxy, xr01, base);         // + w8*xr
            f16x2 a23 = fma_lo4(wxy, xr23, base);
            #pragma unroll
            for (int k = 0; k < 4; ++k) {
                const uint32_t w = wq[5 * o + k];        // (c2k, c2k+1)
                fma_lo(a01, w, fA[2 * k]);  fma_hi(a01, w, fA[2 * k + 1]);
                fma_lo(a23, w, fB[2 * k]);  fma_hi(a23, w, fB[2 * k + 1]);
            }
            const f16x2 z = {(__fp16)0.f, (__fp16)0.f};
            h1A[o] = max2(a01, z);
            h1B[o] = max2(a23, z);
        }

        // ---- layer 2: 8 -> 8, relu ----
        f16x2 h2A[8], h2B[8];
        #pragma unroll
        for (int o = 0; o < 8; ++o) {
            const uint32_t w0 = wq[40 + 4 * o];
            f16x2 a01 = fma_lo4(w0, h1A[0], b2v[o]);
            f16x2 a23 = fma_lo4(w0, h1B[0], b2v[o]);
            fma_hi(a01, w0, h1A[1]);  fma_hi(a23, w0, h1B[1]);
            #pragma unroll
            for (int k = 1; k < 4; ++k) {
                const uint32_t w = wq[40 + 4 * o + k];
                fma_lo(a01, w, h1A[2 * k]);  fma_hi(a01, w, h1A[2 * k + 1]);
                fma_lo(a23, w, h1B[2 * k]);  fma_hi(a23, w, h1B[2 * k + 1]);
            }
            const f16x2 z = {(__fp16)0.f, (__fp16)0.f};
            h2A[o] = max2(a01, z);
            h2B[o] = max2(a23, z);
        }

        // ---- layer 3: 8 -> 1, sigmoid + dice (f32) ----
        f16x2 z01 = fma_lo4(wq[72], h2A[0], b3v);
        f16x2 z23 = fma_lo4(wq[72], h2B[0], b3v);
        fma_hi(z01, wq[72], h2A[1]);  fma_hi(z23, wq[72], h2B[1]);
        #pragma unroll
        for (int k = 1; k < 4; ++k) {
            const uint32_t w = wq[72 + k];
            fma_lo(z01, w, h2A[2 * k]);  fma_hi(z01, w, h2A[2 * k + 1]);
            fma_lo(z23, w, h2B[2 * k]);  fma_hi(z23, w, h2B[2 * k + 1]);
        }

        const float o0 = __builtin_amdgcn_rcpf(1.f + __expf(-(float)z01.x));
        const float o1 = __builtin_amdgcn_rcpf(1.f + __expf(-(float)z01.y));
        const float o2 = __builtin_amdgcn_rcpf(1.f + __expf(-(float)z23.x));
        const float o3 = __builtin_amdgcn_rcpf(1.f + __expf(-(float)z23.y));

        inter = fmaf(o0, t4.x, inter); inter = fmaf(o1, t4.y, inter);
        inter = fmaf(o2, t4.z, inter); inter = fmaf(o3, t4.w, inter);
        ps = fmaf(o0, o0, ps); ps = fmaf(o1, o1, ps);
        ps = fmaf(o2, o2, ps); ps = fmaf(o3, o3, ps);
        ts = fmaf(t4.x, t4.x, ts); ts = fmaf(t4.y, t4.y, ts);
        ts = fmaf(t4.z, t4.z, ts); ts = fmaf(t4.w, t4.w, ts);
    }

    const float m2 = m * m;
    inter *= m2; ps *= m2; ts *= m2;

    #pragma unroll
    for (int off = 32; off > 0; off >>= 1) {
        inter += __shfl_down(inter, off);
        ps    += __shfl_down(ps,    off);
        ts    += __shfl_down(ts,    off);
    }
    __shared__ float red[3][4];
    const int wave = tid >> 6;
    if ((tid & 63) == 0) { red[0][wave] = inter; red[1][wave] = ps; red[2][wave] = ts; }
    __syncthreads();
    if (tid == 0) {
        const int local = (bnu & 63) * CHUNKS + chunk;   // 0..255 within batch b
        red_base[(b * 3 + 0) * 256 + local] = red[0][0] + red[0][1] + red[0][2] + red[0][3];
        red_base[(b * 3 + 1) * 256 + local] = red[1][0] + red[1][1] + red[1][2] + red[1][3];
        red_base[(b * 3 + 2) * 256 + local] = red[2][0] + red[2][1] + red[2][2] + red[2][3];
    }
}

// deterministic epilogue: 24 series (8 b x 3 comps) x 256 partials
__global__ void seg_dice_final(const float* __restrict__ red_base, float* __restrict__ out) {
    __shared__ float red[24][4];
    const int tid = threadIdx.x;  // 128 threads
    if (tid < 96) {
        const int series = tid >> 2;   // 0..23
        const int part   = tid & 3;    // 0..3
        const float4* p = (const float4*)(red_base + series * 256 + part * 64);
        float s = 0.f;
        #pragma unroll
        for (int i = 0; i < 16; ++i) { const float4 v = p[i]; s += (v.x + v.y) + (v.z + v.w); }
        red[series][part] = s;
    }
    __syncthreads();
    if (tid == 0) {
        float acc = 0.f;
        #pragma unroll
        for (int b = 0; b < Bb; ++b) {
            const float inter = red[b*3+0][0] + red[b*3+0][1] + red[b*3+0][2] + red[b*3+0][3];
            const float p2    = red[b*3+1][0] + red[b*3+1][1] + red[b*3+1][2] + red[b*3+1][3];
            const float t2    = red[b*3+2][0] + red[b*3+2][1] + red[b*3+2][2] + red[b*3+2][3];
            acc += 1.0f - (2.0f * inter + 1.0f) / (p2 + t2 + 1.0f);
        }
        out[0] = acc * (1.0f / (float)Bb);
    }
}

extern "C" void kernel_launch(void* const* d_in, const int* in_sizes, int n_in,
                              void* d_out, int out_size, void* d_ws, size_t ws_size,
                              hipStream_t stream) {
    const float* seg_feat    = (const float*)d_in[0];
    const float* conv_weight = (const float*)d_in[1];
    const float* mask        = (const float*)d_in[2];
    const int*   ind         = (const int*)d_in[3];
    const float* target      = (const float*)d_in[4];
    float* out = (float*)d_out;
    float* ws  = (float*)d_ws;

    uint32_t* wtab     = (uint32_t*)ws;
    float*    red_base = ws + RED_OFF;

    pack_weights<<<Bb * Nn, 96, 0, stream>>>(conv_weight, ind, wtab);
    seg_dice_main<<<NBLK, 256, 0, stream>>>(seg_feat, mask, ind, target, wtab, red_base);
    seg_dice_final<<<1, 128, 0, stream>>>(red_base, out);
}